// Round 1
// baseline (328.960 us; speedup 1.0000x reference)
//
#include <hip/hip_runtime.h>
#include <math.h>

#define MS 32
#define NN 1024
#define HH 64
#define CC 10
#define SLOPEF 0.2f

// ---------------------------------------------------------------------------
// GEMM: C[m] (1024x64) = A[m] (1024x1024) @ B (1024x64)
// If bStride==0: B selected among B0/B1/B2 by viewFlag[0] (shared across m).
// Else: B = B0 + m*bStride (per-sample B).
// Block tile 64 rows x 64 cols, 256 threads, 4x4 micro-tile per thread.
// ---------------------------------------------------------------------------
__global__ __launch_bounds__(256) void gemm_n64(
    const float* __restrict__ A, long aStride,
    const float* __restrict__ B0, const float* __restrict__ B1,
    const float* __restrict__ B2, const int* __restrict__ viewFlag,
    long bStride, float* __restrict__ Cmat, long cStride)
{
    __shared__ float As[64][68];
    __shared__ float Bs[64][68];

    const int m = blockIdx.y;
    const int row0 = blockIdx.x * 64;
    const float* A_m = A + (long)m * aStride + (long)row0 * NN;
    const float* B_m;
    if (bStride == 0) {
        int vf = viewFlag[0];
        B_m = (vf == 0) ? B0 : (vf == 1 ? B1 : B2);
    } else {
        B_m = B0 + (long)m * bStride;
    }
    float* C_m = Cmat + (long)m * cStride + (long)row0 * HH;

    const int tid = threadIdx.x;
    const int tx = tid & 15;   // col group (4 cols each)
    const int ty = tid >> 4;   // row group (4 rows each)

    float acc[4][4] = {};

    for (int kc = 0; kc < NN; kc += 64) {
        // stage 64x64 A tile and 64x64 B tile (float4 per thread x4)
        #pragma unroll
        for (int q = 0; q < 4; ++q) {
            int lin = q * 256 + tid;       // float4 slot 0..1023
            int r = lin >> 4;
            int c4 = (lin & 15) << 2;
            float4 va = *reinterpret_cast<const float4*>(A_m + (long)r * NN + kc + c4);
            *reinterpret_cast<float4*>(&As[r][c4]) = va;
            float4 vb = *reinterpret_cast<const float4*>(B_m + (long)(kc + r) * HH + c4);
            *reinterpret_cast<float4*>(&Bs[r][c4]) = vb;
        }
        __syncthreads();

        #pragma unroll
        for (int k4 = 0; k4 < 16; ++k4) {
            float4 a0 = *reinterpret_cast<const float4*>(&As[ty * 4 + 0][k4 * 4]);
            float4 a1 = *reinterpret_cast<const float4*>(&As[ty * 4 + 1][k4 * 4]);
            float4 a2 = *reinterpret_cast<const float4*>(&As[ty * 4 + 2][k4 * 4]);
            float4 a3 = *reinterpret_cast<const float4*>(&As[ty * 4 + 3][k4 * 4]);
            float4 b0 = *reinterpret_cast<const float4*>(&Bs[k4 * 4 + 0][tx * 4]);
            float4 b1 = *reinterpret_cast<const float4*>(&Bs[k4 * 4 + 1][tx * 4]);
            float4 b2 = *reinterpret_cast<const float4*>(&Bs[k4 * 4 + 2][tx * 4]);
            float4 b3 = *reinterpret_cast<const float4*>(&Bs[k4 * 4 + 3][tx * 4]);
            #define ROW_FMA(i, av)                                             \
                acc[i][0] += av.x * b0.x + av.y * b1.x + av.z * b2.x + av.w * b3.x; \
                acc[i][1] += av.x * b0.y + av.y * b1.y + av.z * b2.y + av.w * b3.y; \
                acc[i][2] += av.x * b0.z + av.y * b1.z + av.z * b2.z + av.w * b3.z; \
                acc[i][3] += av.x * b0.w + av.y * b1.w + av.z * b2.w + av.w * b3.w;
            ROW_FMA(0, a0)
            ROW_FMA(1, a1)
            ROW_FMA(2, a2)
            ROW_FMA(3, a3)
            #undef ROW_FMA
        }
        __syncthreads();
    }

    #pragma unroll
    for (int i = 0; i < 4; ++i) {
        float4 v = make_float4(acc[i][0], acc[i][1], acc[i][2], acc[i][3]);
        *reinterpret_cast<float4*>(C_m + (long)(ty * 4 + i) * HH + tx * 4) = v;
    }
}

// ---------------------------------------------------------------------------
// Per-sample iteration kernel: 32 blocks x 1024 threads.
// Runs the collapsed recurrence Y_t = 0.5*Y_{t-1} + 0.5*c_t (x) XW[0,:] + XW,
// tracks u, finds stored iteration k, writes feat_s/sr_s/b_s/u_s and col0_k.
// ---------------------------------------------------------------------------
__global__ __launch_bounds__(1024) void iter_kernel(
    const float* __restrict__ weights,
    const float* __restrict__ XW,
    float* __restrict__ Y,
    const float* __restrict__ fc_w,
    const float* __restrict__ fc_b,
    float* __restrict__ col0_out,
    int* __restrict__ k_out,
    float* __restrict__ out_feat,
    float* __restrict__ out_sr,
    float* __restrict__ out_b,
    float* __restrict__ out_u)
{
    __shared__ float col0[NN];
    __shared__ float cvec[NN];
    __shared__ float xw0[HH];
    __shared__ float partial[16][HH];
    __shared__ float feat[HH];
    __shared__ float sr[CC];
    __shared__ float sS;
    __shared__ float u0s;
    __shared__ int ctrl[2];   // [0]=store, [1]=brk

    const int m = blockIdx.x;
    const int tid = threadIdx.x;
    const float* XWm = XW + (long)m * NN * HH;
    float* Ym = Y + (long)m * NN * HH;

    col0[tid] = weights[(long)m * NN * NN + (long)tid * NN];  // W0[:,0]
    if (tid < HH) xw0[tid] = XWm[tid];                        // XW row 0
    if (tid == 0) u0s = 999.0f;
    __syncthreads();

    const int col = tid & 63;
    const int rg = tid >> 6;   // 0..15

    for (int t = 1; t <= 8; ++t) {
        // c_t and col0 update (1 row per thread)
        {
            float v = col0[tid];
            float cv = (tid < 5 * t && v > 0.0f) ? (1.0f - v) : 0.0f;
            cvec[tid] = cv;
            col0[tid] = 0.5f * (v + cv) + (tid == 0 ? 1.0f : 0.0f);
        }
        __syncthreads();

        // Y update + leaky-relu + per-column partial sums
        float sum = 0.0f;
        const float x0 = xw0[col];
        for (int rr = rg; rr < NN; rr += 16) {
            long idx = (long)rr * HH + col;
            float y = 0.5f * Ym[idx] + 0.5f * cvec[rr] * x0 + XWm[idx];
            Ym[idx] = y;
            sum += (y >= 0.0f) ? y : SLOPEF * y;
        }
        partial[rg][col] = sum;
        __syncthreads();

        if (tid < HH) {
            float s = 0.0f;
            #pragma unroll
            for (int g = 0; g < 16; ++g) s += partial[g][tid];
            feat[tid] = s * (1.0f / NN);
        }
        __syncthreads();

        if (tid < CC) {
            float acc = fc_b[tid];
            for (int h = 0; h < HH; ++h) acc += feat[h] * fc_w[h * CC + tid];
            sr[tid] = log1pf(expf(-fabsf(acc))) + fmaxf(acc, 0.0f);  // softplus
        }
        __syncthreads();

        if (tid == 0) {
            float S = (float)CC;
            for (int c = 0; c < CC; ++c) S += sr[c];
            float u = (float)CC / S;
            int brk = (u >= u0s) || (5 * t >= 40);
            int store = !brk;
            if (store) {
                u0s = u;
                out_u[m] = u;
                k_out[m] = t;
            }
            sS = S;
            ctrl[0] = store;
            ctrl[1] = brk;
        }
        __syncthreads();

        if (ctrl[0]) {
            if (tid < HH) out_feat[m * HH + tid] = feat[tid];
            if (tid < CC) {
                out_sr[m * CC + tid] = sr[tid];
                out_b[m * CC + tid] = sr[tid] / sS;
            }
            col0_out[m * NN + tid] = col0[tid];
        }
        if (ctrl[1]) break;
        __syncthreads();
    }
}

// ---------------------------------------------------------------------------
// Final W write: W_k[i,j] = 0.5^k W0[i,j] + (i==j)*2*(1-0.5^k), col 0 from sim.
// ---------------------------------------------------------------------------
__global__ __launch_bounds__(256) void finalize_W(
    const float* __restrict__ W0, const float* __restrict__ col0k,
    const int* __restrict__ k_arr, float* __restrict__ outW)
{
    const long n4 = (long)MS * NN * NN / 4;
    long i4 = (long)blockIdx.x * blockDim.x + threadIdx.x;
    if (i4 >= n4) return;
    long e = i4 * 4;
    int m = (int)(e >> 20);
    int i = (int)((e >> 10) & 1023);
    int j = (int)(e & 1023);
    int k = k_arr[m];
    float scale = 1.0f / (float)(1 << k);
    float diagadd = 2.0f * (1.0f - scale);

    float4 w = reinterpret_cast<const float4*>(W0)[i4];
    float v0 = scale * w.x + ((i == j + 0) ? diagadd : 0.0f);
    float v1 = scale * w.y + ((i == j + 1) ? diagadd : 0.0f);
    float v2 = scale * w.z + ((i == j + 2) ? diagadd : 0.0f);
    float v3 = scale * w.w + ((i == j + 3) ? diagadd : 0.0f);
    if (j == 0) v0 = col0k[m * NN + i];
    float4 o = make_float4(v0, v1, v2, v3);
    reinterpret_cast<float4*>(outW)[i4] = o;
}

// ---------------------------------------------------------------------------
extern "C" void kernel_launch(void* const* d_in, const int* in_sizes, int n_in,
                              void* d_out, int out_size, void* d_ws, size_t ws_size,
                              hipStream_t stream)
{
    const float* features = (const float*)d_in[0];
    const float* weights  = (const float*)d_in[1];
    const float* w_gnn0   = (const float*)d_in[2];
    const float* w_gnn1   = (const float*)d_in[3];
    const float* w_gnn2   = (const float*)d_in[4];
    const float* fc_w     = (const float*)d_in[5];
    const float* fc_b     = (const float*)d_in[6];
    const int*   viewFlag = (const int*)d_in[7];

    float* out = (float*)d_out;
    float* out_feat = out;                                   // 32*64
    float* outW     = out + (long)MS * HH;                   // 32*1024*1024
    float* out_sr   = outW + (long)MS * NN * NN;             // 32*10
    float* out_b    = out_sr + MS * CC;                      // 32*10
    float* out_u    = out_b + MS * CC;                       // 32

    float* wsf   = (float*)d_ws;
    float* XW    = wsf;                                      // 32*1024*64
    float* Y     = wsf + (long)MS * NN * HH;                 // 32*1024*64
    float* col0k = Y + (long)MS * NN * HH;                   // 32*1024
    int*   k_arr = (int*)(col0k + (long)MS * NN);            // 32

    dim3 gemmGrid(NN / 64, MS);
    // K1: XW = features @ Wg  (Wg chosen by view_flag)
    gemm_n64<<<gemmGrid, 256, 0, stream>>>(features, (long)NN * NN,
                                           w_gnn0, w_gnn1, w_gnn2, viewFlag,
                                           0L, XW, (long)NN * HH);
    // K2: Y0 = weights @ XW (per-sample B)
    gemm_n64<<<gemmGrid, 256, 0, stream>>>(weights, (long)NN * NN,
                                           XW, XW, XW, viewFlag,
                                           (long)NN * HH, Y, (long)NN * HH);
    // K3: collapsed iteration loop
    iter_kernel<<<MS, 1024, 0, stream>>>(weights, XW, Y, fc_w, fc_b,
                                         col0k, k_arr,
                                         out_feat, out_sr, out_b, out_u);
    // K4: final W
    long n4 = (long)MS * NN * NN / 4;
    int blocks = (int)((n4 + 255) / 256);
    finalize_W<<<blocks, 256, 0, stream>>>(weights, col0k, k_arr, outW);
}

// Round 2
// 169.095 us; speedup vs baseline: 1.9454x; 1.9454x over previous
//
#include <hip/hip_runtime.h>
#include <math.h>

#define MS 32
#define NN 1024
#define HH 64
#define CC 10
#define SLOPEF 0.2f

typedef __attribute__((ext_vector_type(8))) short bf16x8;
typedef __attribute__((ext_vector_type(4))) float f32x4;

// Split fp32 into hi/lo bf16 (truncation; lo captures exact residual of hi).
__device__ __forceinline__ void split2(float v, unsigned short& hi, unsigned short& lo) {
    unsigned u = __builtin_bit_cast(unsigned, v);
    hi = (unsigned short)(u >> 16);
    float hf = __builtin_bit_cast(float, u & 0xFFFF0000u);
    float l = v - hf;
    lo = (unsigned short)(__builtin_bit_cast(unsigned, l) >> 16);
}

// ---------------------------------------------------------------------------
// C[m] (1024x64) = A[m] (1024x1024) @ B (1024x64), fp32 in/out, bf16x3 MFMA.
// Block: 64 rows x 64 cols, 256 threads = 4 waves x 16 rows each.
// LDS: A/B tiles split hi/lo bf16, XOR-swizzled ((row&7)<<4) on 16B units.
// ---------------------------------------------------------------------------
__global__ __launch_bounds__(256, 2) void gemm_bf16x3(
    const float* __restrict__ A, long aStride,
    const float* __restrict__ B0, const float* __restrict__ B1,
    const float* __restrict__ B2, const int* __restrict__ viewFlag,
    long bStride, float* __restrict__ Cmat, long cStride)
{
    __shared__ __align__(16) unsigned short Ahi[64 * 64];
    __shared__ __align__(16) unsigned short Alo[64 * 64];
    __shared__ __align__(16) unsigned short Bhi[64 * 64];
    __shared__ __align__(16) unsigned short Blo[64 * 64];

    const int m = blockIdx.y;
    const int row0 = blockIdx.x * 64;
    const float* A_m = A + (long)m * aStride + (long)row0 * NN;
    const float* B_m;
    if (bStride == 0) {
        int vf = viewFlag[0];
        B_m = (vf == 0) ? B0 : (vf == 1 ? B1 : B2);
    } else {
        B_m = B0 + (long)m * bStride;
    }
    float* C_m = Cmat + (long)m * cStride + (long)row0 * HH;

    const int tid = threadIdx.x;
    const int w   = tid >> 6;    // wave 0..3 -> rows [w*16, w*16+16)
    const int l   = tid & 63;
    const int l15 = l & 15;
    const int lg  = l >> 4;      // 0..3

    const int bcol = tid & 63;          // B staging: fixed col
    const int bk0  = (tid >> 6) * 16;   // 16 k values

    f32x4 acc[4] = {};   // 4 col-fragments of 16 cols each

    for (int kc = 0; kc < NN; kc += 64) {
        // ---- issue all global loads first ----
        float4 av[4];
        #pragma unroll
        for (int q = 0; q < 4; ++q) {
            int lin = q * 256 + tid;
            int r   = lin >> 4;
            int c4  = (lin & 15) << 2;
            av[q] = *reinterpret_cast<const float4*>(A_m + (long)r * NN + kc + c4);
        }
        float bv[16];
        #pragma unroll
        for (int i = 0; i < 16; ++i)
            bv[i] = B_m[(long)(kc + bk0 + i) * HH + bcol];

        // ---- convert + stage A (row-major [row][k], swizzled) ----
        #pragma unroll
        for (int q = 0; q < 4; ++q) {
            int lin = q * 256 + tid;
            int r   = lin >> 4;
            int c4  = (lin & 15) << 2;
            ushort4 h, lw;
            split2(av[q].x, h.x, lw.x);
            split2(av[q].y, h.y, lw.y);
            split2(av[q].z, h.z, lw.z);
            split2(av[q].w, h.w, lw.w);
            int byte = (r * 128 + c4 * 2) ^ ((r & 7) << 4);
            *reinterpret_cast<ushort4*>((char*)Ahi + byte) = h;
            *reinterpret_cast<ushort4*>((char*)Alo + byte) = lw;
        }
        // ---- convert + stage B transposed ([col][k], swizzled) ----
        {
            unsigned short bh[16], bl[16];
            #pragma unroll
            for (int i = 0; i < 16; ++i) split2(bv[i], bh[i], bl[i]);
            int base = bcol * 128 + bk0 * 2;
            int sw   = (bcol & 7) << 4;
            #pragma unroll
            for (int half = 0; half < 2; ++half) {
                ushort4 h0, l0, h1, l1;
                h0.x = bh[half*8+0]; h0.y = bh[half*8+1]; h0.z = bh[half*8+2]; h0.w = bh[half*8+3];
                h1.x = bh[half*8+4]; h1.y = bh[half*8+5]; h1.z = bh[half*8+6]; h1.w = bh[half*8+7];
                l0.x = bl[half*8+0]; l0.y = bl[half*8+1]; l0.z = bl[half*8+2]; l0.w = bl[half*8+3];
                l1.x = bl[half*8+4]; l1.y = bl[half*8+5]; l1.z = bl[half*8+6]; l1.w = bl[half*8+7];
                int byte = (base + half * 16) ^ sw;
                *reinterpret_cast<ushort4*>((char*)Bhi + byte)     = h0;
                *reinterpret_cast<ushort4*>((char*)Bhi + byte + 8) = h1;
                *reinterpret_cast<ushort4*>((char*)Blo + byte)     = l0;
                *reinterpret_cast<ushort4*>((char*)Blo + byte + 8) = l1;
            }
        }
        __syncthreads();

        // ---- MFMA: 2 k-slices of 32 ----
        #pragma unroll
        for (int s = 0; s < 2; ++s) {
            int arow  = w * 16 + l15;
            int abyte = (arow * 128 + s * 64 + lg * 16) ^ ((arow & 7) << 4);
            bf16x8 ah = *reinterpret_cast<bf16x8*>((char*)Ahi + abyte);
            bf16x8 al = *reinterpret_cast<bf16x8*>((char*)Alo + abyte);
            #pragma unroll
            for (int fc = 0; fc < 4; ++fc) {
                int col   = fc * 16 + l15;
                int bbyte = (col * 128 + s * 64 + lg * 16) ^ ((col & 7) << 4);
                bf16x8 bh8 = *reinterpret_cast<bf16x8*>((char*)Bhi + bbyte);
                bf16x8 bl8 = *reinterpret_cast<bf16x8*>((char*)Blo + bbyte);
                acc[fc] = __builtin_amdgcn_mfma_f32_16x16x32_bf16(ah, bh8, acc[fc], 0, 0, 0);
                acc[fc] = __builtin_amdgcn_mfma_f32_16x16x32_bf16(ah, bl8, acc[fc], 0, 0, 0);
                acc[fc] = __builtin_amdgcn_mfma_f32_16x16x32_bf16(al, bh8, acc[fc], 0, 0, 0);
            }
        }
        __syncthreads();
    }

    // ---- write C: col = l&15, row = (l>>4)*4 + reg ----
    #pragma unroll
    for (int fc = 0; fc < 4; ++fc) {
        #pragma unroll
        for (int r = 0; r < 4; ++r) {
            int row = w * 16 + lg * 4 + r;
            int col = fc * 16 + l15;
            C_m[(long)row * HH + col] = acc[fc][r];
        }
    }
}

// ---------------------------------------------------------------------------
// Per-sample iteration kernel (unchanged from passing R1 version).
// ---------------------------------------------------------------------------
__global__ __launch_bounds__(1024) void iter_kernel(
    const float* __restrict__ weights,
    const float* __restrict__ XW,
    float* __restrict__ Y,
    const float* __restrict__ fc_w,
    const float* __restrict__ fc_b,
    float* __restrict__ col0_out,
    int* __restrict__ k_out,
    float* __restrict__ out_feat,
    float* __restrict__ out_sr,
    float* __restrict__ out_b,
    float* __restrict__ out_u)
{
    __shared__ float col0[NN];
    __shared__ float cvec[NN];
    __shared__ float xw0[HH];
    __shared__ float partial[16][HH];
    __shared__ float feat[HH];
    __shared__ float sr[CC];
    __shared__ float sS;
    __shared__ float u0s;
    __shared__ int ctrl[2];

    const int m = blockIdx.x;
    const int tid = threadIdx.x;
    const float* XWm = XW + (long)m * NN * HH;
    float* Ym = Y + (long)m * NN * HH;

    col0[tid] = weights[(long)m * NN * NN + (long)tid * NN];
    if (tid < HH) xw0[tid] = XWm[tid];
    if (tid == 0) u0s = 999.0f;
    __syncthreads();

    const int col = tid & 63;
    const int rg = tid >> 6;

    for (int t = 1; t <= 8; ++t) {
        {
            float v = col0[tid];
            float cv = (tid < 5 * t && v > 0.0f) ? (1.0f - v) : 0.0f;
            cvec[tid] = cv;
            col0[tid] = 0.5f * (v + cv) + (tid == 0 ? 1.0f : 0.0f);
        }
        __syncthreads();

        float sum = 0.0f;
        const float x0 = xw0[col];
        for (int rr = rg; rr < NN; rr += 16) {
            long idx = (long)rr * HH + col;
            float y = 0.5f * Ym[idx] + 0.5f * cvec[rr] * x0 + XWm[idx];
            Ym[idx] = y;
            sum += (y >= 0.0f) ? y : SLOPEF * y;
        }
        partial[rg][col] = sum;
        __syncthreads();

        if (tid < HH) {
            float s = 0.0f;
            #pragma unroll
            for (int g = 0; g < 16; ++g) s += partial[g][tid];
            feat[tid] = s * (1.0f / NN);
        }
        __syncthreads();

        if (tid < CC) {
            float acc = fc_b[tid];
            for (int h = 0; h < HH; ++h) acc += feat[h] * fc_w[h * CC + tid];
            sr[tid] = log1pf(expf(-fabsf(acc))) + fmaxf(acc, 0.0f);
        }
        __syncthreads();

        if (tid == 0) {
            float S = (float)CC;
            for (int c = 0; c < CC; ++c) S += sr[c];
            float u = (float)CC / S;
            int brk = (u >= u0s) || (5 * t >= 40);
            int store = !brk;
            if (store) {
                u0s = u;
                out_u[m] = u;
                k_out[m] = t;
            }
            sS = S;
            ctrl[0] = store;
            ctrl[1] = brk;
        }
        __syncthreads();

        if (ctrl[0]) {
            if (tid < HH) out_feat[m * HH + tid] = feat[tid];
            if (tid < CC) {
                out_sr[m * CC + tid] = sr[tid];
                out_b[m * CC + tid] = sr[tid] / sS;
            }
            col0_out[m * NN + tid] = col0[tid];
        }
        if (ctrl[1]) break;
        __syncthreads();
    }
}

// ---------------------------------------------------------------------------
// Final W write (unchanged).
// ---------------------------------------------------------------------------
__global__ __launch_bounds__(256) void finalize_W(
    const float* __restrict__ W0, const float* __restrict__ col0k,
    const int* __restrict__ k_arr, float* __restrict__ outW)
{
    const long n4 = (long)MS * NN * NN / 4;
    long i4 = (long)blockIdx.x * blockDim.x + threadIdx.x;
    if (i4 >= n4) return;
    long e = i4 * 4;
    int m = (int)(e >> 20);
    int i = (int)((e >> 10) & 1023);
    int j = (int)(e & 1023);
    int k = k_arr[m];
    float scale = 1.0f / (float)(1 << k);
    float diagadd = 2.0f * (1.0f - scale);

    float4 w = reinterpret_cast<const float4*>(W0)[i4];
    float v0 = scale * w.x + ((i == j + 0) ? diagadd : 0.0f);
    float v1 = scale * w.y + ((i == j + 1) ? diagadd : 0.0f);
    float v2 = scale * w.z + ((i == j + 2) ? diagadd : 0.0f);
    float v3 = scale * w.w + ((i == j + 3) ? diagadd : 0.0f);
    if (j == 0) v0 = col0k[m * NN + i];
    float4 o = make_float4(v0, v1, v2, v3);
    reinterpret_cast<float4*>(outW)[i4] = o;
}

// ---------------------------------------------------------------------------
extern "C" void kernel_launch(void* const* d_in, const int* in_sizes, int n_in,
                              void* d_out, int out_size, void* d_ws, size_t ws_size,
                              hipStream_t stream)
{
    const float* features = (const float*)d_in[0];
    const float* weights  = (const float*)d_in[1];
    const float* w_gnn0   = (const float*)d_in[2];
    const float* w_gnn1   = (const float*)d_in[3];
    const float* w_gnn2   = (const float*)d_in[4];
    const float* fc_w     = (const float*)d_in[5];
    const float* fc_b     = (const float*)d_in[6];
    const int*   viewFlag = (const int*)d_in[7];

    float* out = (float*)d_out;
    float* out_feat = out;                                   // 32*64
    float* outW     = out + (long)MS * HH;                   // 32*1024*1024
    float* out_sr   = outW + (long)MS * NN * NN;             // 32*10
    float* out_b    = out_sr + MS * CC;                      // 32*10
    float* out_u    = out_b + MS * CC;                       // 32

    float* wsf   = (float*)d_ws;
    float* XW    = wsf;                                      // 32*1024*64
    float* Y     = wsf + (long)MS * NN * HH;                 // 32*1024*64
    float* col0k = Y + (long)MS * NN * HH;                   // 32*1024
    int*   k_arr = (int*)(col0k + (long)MS * NN);            // 32

    dim3 gemmGrid(NN / 64, MS);
    // K1: XW = features @ Wg
    gemm_bf16x3<<<gemmGrid, 256, 0, stream>>>(features, (long)NN * NN,
                                              w_gnn0, w_gnn1, w_gnn2, viewFlag,
                                              0L, XW, (long)NN * HH);
    // K2: Y0 = weights @ XW
    gemm_bf16x3<<<gemmGrid, 256, 0, stream>>>(weights, (long)NN * NN,
                                              XW, XW, XW, viewFlag,
                                              (long)NN * HH, Y, (long)NN * HH);
    // K3: collapsed iteration loop
    iter_kernel<<<MS, 1024, 0, stream>>>(weights, XW, Y, fc_w, fc_b,
                                         col0k, k_arr,
                                         out_feat, out_sr, out_b, out_u);
    // K4: final W
    long n4 = (long)MS * NN * NN / 4;
    int blocks = (int)((n4 + 255) / 256);
    finalize_W<<<blocks, 256, 0, stream>>>(weights, col0k, k_arr, outW);
}

// Round 3
// 133.701 us; speedup vs baseline: 2.4604x; 1.2647x over previous
//
#include <hip/hip_runtime.h>
#include <math.h>

#define MS 32
#define NN 1024
#define HH 64
#define CC 10
#define SLOPEF 0.2f

typedef __attribute__((ext_vector_type(8))) short bf16x8;
typedef __attribute__((ext_vector_type(4))) float f32x4;

// Split fp32 into hi/lo bf16 (truncation; lo captures residual of hi).
__device__ __forceinline__ void split2(float v, unsigned short& hi, unsigned short& lo) {
    unsigned u = __builtin_bit_cast(unsigned, v);
    hi = (unsigned short)(u >> 16);
    float hf = __builtin_bit_cast(float, u & 0xFFFF0000u);
    float l = v - hf;
    lo = (unsigned short)(__builtin_bit_cast(unsigned, l) >> 16);
}

// ---------------------------------------------------------------------------
// C[m] (1024x64) = A[m] (1024x1024) @ B (1024x64), fp32 in/out, bf16x3 MFMA.
// Block: 64 rows x 64 cols, 256 threads = 4 waves x 16 rows each.
// FUSED=0: write C to Cmat (used for XW = features @ Wg).
// FUSED=1: Y0 stays in registers; epilogue computes, for t=1..8,
//   Y_t = a_t*Y0 + b_t(row)*x0[col] + g_t*XW[row][col]  (closed-form recurrence)
//   and emits per-block per-column leaky-relu row-sums to Cmat (= partials).
// ---------------------------------------------------------------------------
template <int FUSED>
__global__ __launch_bounds__(256, 2) void gemm_bf16x3(
    const float* __restrict__ A, long aStride,
    const float* __restrict__ B0, const float* __restrict__ B1,
    const float* __restrict__ B2, const int* __restrict__ viewFlag,
    long bStride, float* __restrict__ Cmat, long cStride)
{
    __shared__ __align__(16) unsigned short Ahi[64 * 64];
    __shared__ __align__(16) unsigned short Alo[64 * 64];
    __shared__ __align__(16) unsigned short Bhi[64 * 64];
    __shared__ __align__(16) unsigned short Blo[64 * 64];
    __shared__ float x0s[64];
    __shared__ float red2[4][8][64];

    const int m = blockIdx.y;
    const int row0 = blockIdx.x * 64;
    const float* A_m = A + (long)m * aStride + (long)row0 * NN;
    const float* B_m;
    if (bStride == 0) {
        int vf = viewFlag[0];
        B_m = (vf == 0) ? B0 : (vf == 1 ? B1 : B2);
    } else {
        B_m = B0 + (long)m * bStride;
    }

    const int tid = threadIdx.x;
    const int w   = tid >> 6;    // wave 0..3 -> rows [w*16, w*16+16)
    const int l   = tid & 63;
    const int l15 = l & 15;
    const int lg  = l >> 4;      // 0..3

    const int bcol = tid & 63;          // B staging: fixed col
    const int bk0  = (tid >> 6) * 16;   // 16 k values

    f32x4 acc[4] = {};   // 4 col-fragments of 16 cols each

    for (int kc = 0; kc < NN; kc += 64) {
        float4 av[4];
        #pragma unroll
        for (int q = 0; q < 4; ++q) {
            int lin = q * 256 + tid;
            int r   = lin >> 4;
            int c4  = (lin & 15) << 2;
            av[q] = *reinterpret_cast<const float4*>(A_m + (long)r * NN + kc + c4);
        }
        float bv[16];
        #pragma unroll
        for (int i = 0; i < 16; ++i)
            bv[i] = B_m[(long)(kc + bk0 + i) * HH + bcol];

        #pragma unroll
        for (int q = 0; q < 4; ++q) {
            int lin = q * 256 + tid;
            int r   = lin >> 4;
            int c4  = (lin & 15) << 2;
            ushort4 h, lw;
            split2(av[q].x, h.x, lw.x);
            split2(av[q].y, h.y, lw.y);
            split2(av[q].z, h.z, lw.z);
            split2(av[q].w, h.w, lw.w);
            int byte = (r * 128 + c4 * 2) ^ ((r & 7) << 4);
            *reinterpret_cast<ushort4*>((char*)Ahi + byte) = h;
            *reinterpret_cast<ushort4*>((char*)Alo + byte) = lw;
        }
        {
            unsigned short bh[16], bl[16];
            #pragma unroll
            for (int i = 0; i < 16; ++i) split2(bv[i], bh[i], bl[i]);
            int base = bcol * 128 + bk0 * 2;
            int sw   = (bcol & 7) << 4;
            #pragma unroll
            for (int half = 0; half < 2; ++half) {
                ushort4 h0, l0, h1, l1;
                h0.x = bh[half*8+0]; h0.y = bh[half*8+1]; h0.z = bh[half*8+2]; h0.w = bh[half*8+3];
                h1.x = bh[half*8+4]; h1.y = bh[half*8+5]; h1.z = bh[half*8+6]; h1.w = bh[half*8+7];
                l0.x = bl[half*8+0]; l0.y = bl[half*8+1]; l0.z = bl[half*8+2]; l0.w = bl[half*8+3];
                l1.x = bl[half*8+4]; l1.y = bl[half*8+5]; l1.z = bl[half*8+6]; l1.w = bl[half*8+7];
                int byte = (base + half * 16) ^ sw;
                *reinterpret_cast<ushort4*>((char*)Bhi + byte)     = h0;
                *reinterpret_cast<ushort4*>((char*)Bhi + byte + 8) = h1;
                *reinterpret_cast<ushort4*>((char*)Blo + byte)     = l0;
                *reinterpret_cast<ushort4*>((char*)Blo + byte + 8) = l1;
            }
        }
        __syncthreads();

        #pragma unroll
        for (int s = 0; s < 2; ++s) {
            int arow  = w * 16 + l15;
            int abyte = (arow * 128 + s * 64 + lg * 16) ^ ((arow & 7) << 4);
            bf16x8 ah = *reinterpret_cast<bf16x8*>((char*)Ahi + abyte);
            bf16x8 al = *reinterpret_cast<bf16x8*>((char*)Alo + abyte);
            #pragma unroll
            for (int fc = 0; fc < 4; ++fc) {
                int col   = fc * 16 + l15;
                int bbyte = (col * 128 + s * 64 + lg * 16) ^ ((col & 7) << 4);
                bf16x8 bh8 = *reinterpret_cast<bf16x8*>((char*)Bhi + bbyte);
                bf16x8 bl8 = *reinterpret_cast<bf16x8*>((char*)Blo + bbyte);
                acc[fc] = __builtin_amdgcn_mfma_f32_16x16x32_bf16(ah, bh8, acc[fc], 0, 0, 0);
                acc[fc] = __builtin_amdgcn_mfma_f32_16x16x32_bf16(ah, bl8, acc[fc], 0, 0, 0);
                acc[fc] = __builtin_amdgcn_mfma_f32_16x16x32_bf16(al, bh8, acc[fc], 0, 0, 0);
            }
        }
        __syncthreads();
    }

    if constexpr (!FUSED) {
        float* C_m = Cmat + (long)m * cStride + (long)row0 * HH;
        #pragma unroll
        for (int fc = 0; fc < 4; ++fc) {
            #pragma unroll
            for (int r = 0; r < 4; ++r) {
                int row = w * 16 + lg * 4 + r;
                int col = fc * 16 + l15;
                C_m[(long)row * HH + col] = acc[fc][r];
            }
        }
    } else {
        // ---- fused 8-iteration epilogue ----
        if (tid < 64) x0s[tid] = B_m[tid];   // XW row 0
        __syncthreads();

        int grows[4]; float v[4], bc[4];
        #pragma unroll
        for (int r = 0; r < 4; ++r) {
            int lrow = w * 16 + lg * 4 + r;
            grows[r] = row0 + lrow;
            v[r] = A_m[(long)lrow * NN];     // W0[row, 0]
            bc[r] = 0.0f;
        }
        float xwv[4][4];
        #pragma unroll
        for (int fc = 0; fc < 4; ++fc) {
            int col = fc * 16 + l15;
            #pragma unroll
            for (int r = 0; r < 4; ++r)
                xwv[fc][r] = B_m[(long)grows[r] * HH + col];
        }

        float alpha = 1.0f, gamma = 0.0f;
        #pragma unroll
        for (int t = 1; t <= 8; ++t) {
            #pragma unroll
            for (int r = 0; r < 4; ++r) {
                float c = (grows[r] < 5 * t && v[r] > 0.0f) ? (1.0f - v[r]) : 0.0f;
                bc[r] = 0.5f * (bc[r] + c);
                v[r]  = 0.5f * (v[r] + c) + (grows[r] == 0 ? 1.0f : 0.0f);
            }
            alpha *= 0.5f;
            gamma = 0.5f * gamma + 1.0f;
            #pragma unroll
            for (int fc = 0; fc < 4; ++fc) {
                float x0c = x0s[fc * 16 + l15];
                float s = 0.0f;
                #pragma unroll
                for (int r = 0; r < 4; ++r) {
                    float y = alpha * acc[fc][r] + bc[r] * x0c + gamma * xwv[fc][r];
                    s += (y >= 0.0f) ? y : SLOPEF * y;
                }
                s += __shfl_xor(s, 16);
                s += __shfl_xor(s, 32);
                if (l < 16) red2[w][t - 1][fc * 16 + l] = s;
            }
        }
        __syncthreads();
        if (tid < 512) {
            int t8 = tid >> 6, col = tid & 63;
            float p = red2[0][t8][col] + red2[1][t8][col] +
                      red2[2][t8][col] + red2[3][t8][col];
            Cmat[(((long)m * 16 + blockIdx.x) * 8 + t8) * 64 + col] = p;
        }
    }
}

// ---------------------------------------------------------------------------
// Per-sample decision kernel: reduce partials -> feat_t -> sr_t -> u_t,
// break scan -> k; write small outputs + col0 simulation.
// ---------------------------------------------------------------------------
__global__ __launch_bounds__(512) void decide_kernel(
    const float* __restrict__ partials,
    const float* __restrict__ weights,
    const float* __restrict__ fc_w,
    const float* __restrict__ fc_b,
    float* __restrict__ col0k,
    int* __restrict__ k_arr,
    float* __restrict__ out_feat,
    float* __restrict__ out_sr,
    float* __restrict__ out_b,
    float* __restrict__ out_u)
{
    __shared__ float feat[8][64];
    __shared__ float sr_all[8][CC];
    __shared__ float Ss[8], us[8];
    __shared__ int ksh;

    const int m = blockIdx.x;
    const int tid = threadIdx.x;

    {
        int t8 = tid >> 6, col = tid & 63;
        float s = 0.0f;
        for (int bx = 0; bx < 16; ++bx)
            s += partials[(((long)m * 16 + bx) * 8 + t8) * 64 + col];
        feat[t8][col] = s * (1.0f / NN);
    }
    __syncthreads();

    if (tid < 80) {
        int t8 = tid / 10, c = tid % 10;
        float a = fc_b[c];
        for (int h = 0; h < HH; ++h) a += feat[t8][h] * fc_w[h * CC + c];
        sr_all[t8][c] = log1pf(expf(-fabsf(a))) + fmaxf(a, 0.0f);   // softplus
    }
    __syncthreads();

    if (tid < 8) {
        float S = (float)CC;
        for (int c = 0; c < CC; ++c) S += sr_all[tid][c];
        Ss[tid] = S;
        us[tid] = (float)CC / S;
    }
    __syncthreads();

    if (tid == 0) {
        float u0 = 999.0f; int k = 1;
        for (int tt = 1; tt <= 8; ++tt) {
            float u = us[tt - 1];
            int brk = (u >= u0) || (tt == 8);
            if (!brk) { k = tt; u0 = u; } else break;
        }
        ksh = k;
        k_arr[m] = k;
        out_u[m] = us[k - 1];
    }
    __syncthreads();

    const int k = ksh;
    if (tid < 64) out_feat[m * HH + tid] = feat[k - 1][tid];
    if (tid < CC) {
        out_sr[m * CC + tid] = sr_all[k - 1][tid];
        out_b[m * CC + tid]  = sr_all[k - 1][tid] / Ss[k - 1];
    }
    for (int i = tid; i < NN; i += 512) {
        float v = weights[(long)m * NN * NN + (long)i * NN];
        for (int s = 1; s <= k; ++s) {
            float c = (i < 5 * s && v > 0.0f) ? (1.0f - v) : 0.0f;
            v = 0.5f * (v + c) + (i == 0 ? 1.0f : 0.0f);
        }
        col0k[m * NN + i] = v;
    }
}

// ---------------------------------------------------------------------------
// Final W write: W_k[i,j] = 0.5^k W0[i,j] + (i==j)*2*(1-0.5^k), col 0 from sim.
// ---------------------------------------------------------------------------
__global__ __launch_bounds__(256) void finalize_W(
    const float* __restrict__ W0, const float* __restrict__ col0k,
    const int* __restrict__ k_arr, float* __restrict__ outW)
{
    const long n4 = (long)MS * NN * NN / 4;
    long i4 = (long)blockIdx.x * blockDim.x + threadIdx.x;
    if (i4 >= n4) return;
    long e = i4 * 4;
    int m = (int)(e >> 20);
    int i = (int)((e >> 10) & 1023);
    int j = (int)(e & 1023);
    int k = k_arr[m];
    float scale = 1.0f / (float)(1 << k);
    float diagadd = 2.0f * (1.0f - scale);

    float4 wv = reinterpret_cast<const float4*>(W0)[i4];
    float v0 = scale * wv.x + ((i == j + 0) ? diagadd : 0.0f);
    float v1 = scale * wv.y + ((i == j + 1) ? diagadd : 0.0f);
    float v2 = scale * wv.z + ((i == j + 2) ? diagadd : 0.0f);
    float v3 = scale * wv.w + ((i == j + 3) ? diagadd : 0.0f);
    if (j == 0) v0 = col0k[m * NN + i];
    float4 o = make_float4(v0, v1, v2, v3);
    reinterpret_cast<float4*>(outW)[i4] = o;
}

// ---------------------------------------------------------------------------
extern "C" void kernel_launch(void* const* d_in, const int* in_sizes, int n_in,
                              void* d_out, int out_size, void* d_ws, size_t ws_size,
                              hipStream_t stream)
{
    const float* features = (const float*)d_in[0];
    const float* weights  = (const float*)d_in[1];
    const float* w_gnn0   = (const float*)d_in[2];
    const float* w_gnn1   = (const float*)d_in[3];
    const float* w_gnn2   = (const float*)d_in[4];
    const float* fc_w     = (const float*)d_in[5];
    const float* fc_b     = (const float*)d_in[6];
    const int*   viewFlag = (const int*)d_in[7];

    float* out = (float*)d_out;
    float* out_feat = out;                                   // 32*64
    float* outW     = out + (long)MS * HH;                   // 32*1024*1024
    float* out_sr   = outW + (long)MS * NN * NN;             // 32*10
    float* out_b    = out_sr + MS * CC;                      // 32*10
    float* out_u    = out_b + MS * CC;                       // 32

    float* wsf      = (float*)d_ws;
    float* XW       = wsf;                                   // 32*1024*64 = 2M floats
    float* partials = XW + (long)MS * NN * HH;               // 32*16*8*64 = 256K floats
    float* col0k    = partials + (long)MS * 16 * 8 * 64;     // 32*1024
    int*   k_arr    = (int*)(col0k + (long)MS * NN);         // 32

    dim3 gemmGrid(NN / 64, MS);
    // K1: XW = features @ Wg
    gemm_bf16x3<0><<<gemmGrid, 256, 0, stream>>>(features, (long)NN * NN,
                                                 w_gnn0, w_gnn1, w_gnn2, viewFlag,
                                                 0L, XW, (long)NN * HH);
    // K2: Y0 = weights @ XW  + fused 8-iteration epilogue -> partials
    gemm_bf16x3<1><<<gemmGrid, 256, 0, stream>>>(weights, (long)NN * NN,
                                                 XW, XW, XW, viewFlag,
                                                 (long)NN * HH, partials, 0L);
    // K3: per-sample decision + col0 sim
    decide_kernel<<<MS, 512, 0, stream>>>(partials, weights, fc_w, fc_b,
                                          col0k, k_arr,
                                          out_feat, out_sr, out_b, out_u);
    // K4: final W
    long n4 = (long)MS * NN * NN / 4;
    int blocks = (int)((n4 + 255) / 256);
    finalize_W<<<blocks, 256, 0, stream>>>(weights, col0k, k_arr, outW);
}